// Round 1
// baseline (1041.180 us; speedup 1.0000x reference)
//
#include <hip/hip_runtime.h>
#include <hip/hip_bf16.h>
#include <math.h>

// Problem constants (from reference setup_inputs)
#define BB 32
#define NN 1024
#define DD 64
#define TT 2048

template<int CTRL>
__device__ __forceinline__ float dpp_mov_f(float v) {
    int i = __builtin_amdgcn_update_dpp(__float_as_int(v), __float_as_int(v),
                                        CTRL, 0xF, 0xF, false);
    return __int_as_float(i);
}

// All-lanes butterfly reduce over groups of 2^GB lanes.
// GB=4: pure-VALU DPP (xor1, xor2, xor4-equiv half-mirror, xor8-equiv mirror).
// GB=6: adds two LDS shuffles (xor16, xor32).
template<int GB>
__device__ __forceinline__ float groupMax(float v) {
    v = fmaxf(v, dpp_mov_f<0x0B1>(v));  // quad_perm [1,0,3,2]  -> xor1
    v = fmaxf(v, dpp_mov_f<0x04E>(v));  // quad_perm [2,3,0,1]  -> xor2
    v = fmaxf(v, dpp_mov_f<0x141>(v));  // row_half_mirror      -> xor4 (given quad-uniform)
    v = fmaxf(v, dpp_mov_f<0x140>(v));  // row_mirror           -> xor8 (given 8-uniform)
    if constexpr (GB == 6) {
        v = fmaxf(v, __shfl_xor(v, 16));
        v = fmaxf(v, __shfl_xor(v, 32));
    }
    return v;
}

template<int GB>
__device__ __forceinline__ float groupSum(float v) {
    v += dpp_mov_f<0x0B1>(v);
    v += dpp_mov_f<0x04E>(v);
    v += dpp_mov_f<0x141>(v);
    v += dpp_mov_f<0x140>(v);
    if constexpr (GB == 6) {
        v += __shfl_xor(v, 16);
        v += __shfl_xor(v, 32);
    }
    return v;
}

// One workgroup = one (batch, t-chunk of 256 columns). Each thread owns one
// W column (64 VGPRs) and its running alpha. Sequential over n; per n emit
// per-group softmax partials (m, s, p). No barriers, no LDS in the loop.
template<int GB>
__global__ __launch_bounds__(256)
void scan_kernel(const float* __restrict__ data,
                 const float* __restrict__ targets,
                 const float* __restrict__ W,
                 float* __restrict__ mP,
                 float* __restrict__ sP,
                 float* __restrict__ pP)
{
    constexpr int CHUNKS = TT / 256;           // 8
    constexpr int PPN    = TT >> GB;           // partials per (b,n)
    const int blk   = blockIdx.x;
    const int b     = blk >> 3;                // / CHUNKS
    const int chunk = blk & (CHUNKS - 1);
    const int tid   = threadIdx.x;
    const int lane  = tid & 63;
    const int col   = chunk * 256 + tid;

    // W column -> registers (coalesced across tid for each d)
    float w[DD];
#pragma unroll
    for (int d = 0; d < DD; ++d) w[d] = W[(size_t)d * TT + col];

    const float* xb = data + (size_t)b * NN * DD;
    const float* tb = targets + (size_t)b * NN;

    const int  k      = (chunk * 256 + (tid & ~((1 << GB) - 1))) >> GB;
    const bool writer = (lane & ((1 << GB) - 1)) == 0;
    const size_t base0 = (size_t)b * NN * PPN + k;

    float alpha = 0.0f;

    for (int n = 0; n < NN; ++n) {
        const float* xr = xb + n * DD;   // uniform address -> scalar loads
        float a0 = 0.f, a1 = 0.f, a2 = 0.f, a3 = 0.f;
#pragma unroll
        for (int d = 0; d < DD; d += 4) {
            a0 = fmaf(xr[d + 0], w[d + 0], a0);
            a1 = fmaf(xr[d + 1], w[d + 1], a1);
            a2 = fmaf(xr[d + 2], w[d + 2], a2);
            a3 = fmaf(xr[d + 3], w[d + 3], a3);
        }
        const float xw = (a0 + a1) + (a2 + a3);

        // exclusive-prefix softmax partials (alpha BEFORE adding point n)
        const float m  = groupMax<GB>(alpha);
        const float e  = __expf(alpha - m);
        const float pe = e * xw;
        const float s  = groupSum<GB>(e);
        const float p  = groupSum<GB>(pe);

        if (writer) {
            const size_t idx = base0 + (size_t)n * PPN;
            mP[idx] = m; sP[idx] = s; pP[idx] = p;
        }

        const float diff = tb[n] - xw;   // uniform scalar load of target
        alpha = fmaf(diff * diff, -0.5f, alpha);
    }
}

// One wave per (b,n): merge PPN partials with log-sum-exp combine.
template<int PPN>
__global__ __launch_bounds__(256)
void combine_kernel(const float* __restrict__ mP,
                    const float* __restrict__ sP,
                    const float* __restrict__ pP,
                    float* __restrict__ out)
{
    const int wgid = blockIdx.x * 4 + (threadIdx.x >> 6);   // = b*NN + n
    const int lane = threadIdx.x & 63;
    const size_t base = (size_t)wgid * PPN;

    float m = -INFINITY, s = 0.0f, p = 0.0f;
    if constexpr (PPN >= 64) {
#pragma unroll
        for (int j = 0; j < PPN / 64; ++j) {
            const size_t idx = base + lane + j * 64;
            const float mk = mP[idx], sk = sP[idx], pk = pP[idx];
            const float M  = fmaxf(m, mk);
            const float e1 = __expf(m - M), e2 = __expf(mk - M);
            s = s * e1 + sk * e2;
            p = p * e1 + pk * e2;
            m = M;
        }
    } else {
        if (lane < PPN) {
            m = mP[base + lane]; s = sP[base + lane]; p = pP[base + lane];
        }
    }

    // 64-lane butterfly merge
#pragma unroll
    for (int off = 1; off < 64; off <<= 1) {
        const float mo = __shfl_xor(m, off);
        const float so = __shfl_xor(s, off);
        const float po = __shfl_xor(p, off);
        const float M  = fmaxf(m, mo);
        const float e1 = __expf(m - M), e2 = __expf(mo - M);
        s = s * e1 + so * e2;
        p = p * e1 + po * e2;
        m = M;
    }

    if (lane == 0) out[wgid] = p / s;
}

extern "C" void kernel_launch(void* const* d_in, const int* in_sizes, int n_in,
                              void* d_out, int out_size, void* d_ws, size_t ws_size,
                              hipStream_t stream)
{
    (void)in_sizes; (void)n_in; (void)out_size;
    const float* data    = (const float*)d_in[0];
    const float* targets = (const float*)d_in[1];
    const float* W       = (const float*)d_in[2];
    float* out = (float*)d_out;

    const size_t plane16 = (size_t)BB * NN * (TT >> 4);   // GB=4: 128 partials/(b,n)
    const size_t plane64 = (size_t)BB * NN * (TT >> 6);   // GB=6: 32 partials/(b,n)

    if (ws_size >= plane16 * 3 * sizeof(float)) {
        float* mP = (float*)d_ws;
        float* sP = mP + plane16;
        float* pP = sP + plane16;
        scan_kernel<4><<<BB * (TT / 256), 256, 0, stream>>>(data, targets, W, mP, sP, pP);
        combine_kernel<128><<<(BB * NN) / 4, 256, 0, stream>>>(mP, sP, pP, out);
    } else {
        float* mP = (float*)d_ws;
        float* sP = mP + plane64;
        float* pP = sP + plane64;
        scan_kernel<6><<<BB * (TT / 256), 256, 0, stream>>>(data, targets, W, mP, sP, pP);
        combine_kernel<32><<<(BB * NN) / 4, 256, 0, stream>>>(mP, sP, pP, out);
    }
}

// Round 2
// 383.287 us; speedup vs baseline: 2.7165x; 2.7165x over previous
//
#include <hip/hip_runtime.h>
#include <hip/hip_bf16.h>
#include <math.h>

// Problem constants (from reference setup_inputs)
#define BB 32
#define NN 1024
#define DD 64
#define TT 2048
#define CHUNKS (TT / 256)   // 8 column-chunks of 256

template<int CTRL>
__device__ __forceinline__ float dpp_mov_f(float v) {
    int i = __builtin_amdgcn_update_dpp(__float_as_int(v), __float_as_int(v),
                                        CTRL, 0xF, 0xF, false);
    return __int_as_float(i);
}

// All-lanes butterfly reduce over groups of 2^GB lanes.
// GB=4: pure-VALU DPP (xor1, xor2, half-mirror=xor4, mirror=xor8).
// GB=6: adds two LDS shuffles (xor16, xor32).
template<int GB>
__device__ __forceinline__ float groupMax(float v) {
    v = fmaxf(v, dpp_mov_f<0x0B1>(v));  // quad_perm [1,0,3,2]  -> xor1
    v = fmaxf(v, dpp_mov_f<0x04E>(v));  // quad_perm [2,3,0,1]  -> xor2
    v = fmaxf(v, dpp_mov_f<0x141>(v));  // row_half_mirror      -> xor4
    v = fmaxf(v, dpp_mov_f<0x140>(v));  // row_mirror           -> xor8
    if constexpr (GB == 6) {
        v = fmaxf(v, __shfl_xor(v, 16));
        v = fmaxf(v, __shfl_xor(v, 32));
    }
    return v;
}

template<int GB>
__device__ __forceinline__ float groupSum(float v) {
    v += dpp_mov_f<0x0B1>(v);
    v += dpp_mov_f<0x04E>(v);
    v += dpp_mov_f<0x141>(v);
    v += dpp_mov_f<0x140>(v);
    if constexpr (GB == 6) {
        v += __shfl_xor(v, 16);
        v += __shfl_xor(v, 32);
    }
    return v;
}

// dot(x_row, w) with identical FP order in both passes
__device__ __forceinline__ float dot64(const float* __restrict__ xr,
                                       const float* __restrict__ w) {
    float a0 = 0.f, a1 = 0.f, a2 = 0.f, a3 = 0.f;
#pragma unroll
    for (int d = 0; d < DD; d += 4) {
        a0 = fmaf(xr[d + 0], w[d + 0], a0);
        a1 = fmaf(xr[d + 1], w[d + 1], a1);
        a2 = fmaf(xr[d + 2], w[d + 2], a2);
        a3 = fmaf(xr[d + 3], w[d + 3], a3);
    }
    return (a0 + a1) + (a2 + a3);
}

// Pass A: per-(b, t, segment) sum of log-probs. Fully parallel over segments.
template<int SEG>
__global__ __launch_bounds__(256, 4)
void segsum_kernel(const float* __restrict__ data,
                   const float* __restrict__ targets,
                   const float* __restrict__ W,
                   float* __restrict__ segsum)
{
    constexpr int NSEG = NN / SEG;
    const int blk   = blockIdx.x;
    const int s     = blk % SEG;
    const int rem   = blk / SEG;
    const int chunk = rem % CHUNKS;
    const int b     = rem / CHUNKS;
    const int tid   = threadIdx.x;
    const int col   = chunk * 256 + tid;

    float w[DD];
#pragma unroll
    for (int d = 0; d < DD; ++d) w[d] = W[(size_t)d * TT + col];

    const float* xb = data + (size_t)b * NN * DD;
    const float* tb = targets + (size_t)b * NN;

    const int n0 = s * NSEG;
    float acc = 0.0f;
    for (int n = n0; n < n0 + NSEG; ++n) {
        const float xw   = dot64(xb + (size_t)n * DD, w);  // uniform x -> s_loads
        const float diff = tb[n] - xw;
        acc = fmaf(diff * diff, -0.5f, acc);
    }
    segsum[((size_t)b * SEG + s) * TT + col] = acc;
}

// Pass B: per-(b, t-chunk, segment) local scan seeded with segment prefix;
// emits per-2^GB-lane-group softmax partials (m, s, p) for every n.
template<int SEG, int GB>
__global__ __launch_bounds__(256, 4)
void scan_kernel(const float* __restrict__ data,
                 const float* __restrict__ targets,
                 const float* __restrict__ W,
                 const float* __restrict__ segsum,
                 float* __restrict__ mP,
                 float* __restrict__ sP,
                 float* __restrict__ pP)
{
    constexpr int NSEG = NN / SEG;
    constexpr int PPN  = TT >> GB;            // partials per (b,n)
    const int blk   = blockIdx.x;
    const int s     = blk % SEG;
    const int rem   = blk / SEG;
    const int chunk = rem % CHUNKS;
    const int b     = rem / CHUNKS;
    const int tid   = threadIdx.x;
    const int lane  = tid & 63;
    const int col   = chunk * 256 + tid;

    float w[DD];
#pragma unroll
    for (int d = 0; d < DD; ++d) w[d] = W[(size_t)d * TT + col];

    const float* xb = data + (size_t)b * NN * DD;
    const float* tb = targets + (size_t)b * NN;

    const int  k      = (chunk * 256 + (tid & ~((1 << GB) - 1))) >> GB;
    const bool writer = (lane & ((1 << GB) - 1)) == 0;
    const size_t base0 = (size_t)b * NN * PPN + k;

    // exclusive segment prefix
    float alpha = 0.0f;
    if constexpr (SEG > 1) {
        for (int s2 = 0; s2 < s; ++s2)
            alpha += segsum[((size_t)b * SEG + s2) * TT + col];
    }

    const int n0 = s * NSEG;
    for (int n = n0; n < n0 + NSEG; ++n) {
        const float xw = dot64(xb + (size_t)n * DD, w);

        // exclusive-prefix softmax partials (alpha BEFORE adding point n)
        const float m  = groupMax<GB>(alpha);
        const float e  = __expf(alpha - m);
        const float pe = e * xw;
        const float sv = groupSum<GB>(e);
        const float pv = groupSum<GB>(pe);

        if (writer) {
            const size_t idx = base0 + (size_t)n * PPN;
            mP[idx] = m; sP[idx] = sv; pP[idx] = pv;
        }

        const float diff = tb[n] - xw;
        alpha = fmaf(diff * diff, -0.5f, alpha);
    }
}

// Pass C: one wave per (b,n): merge PPN partials with log-sum-exp combine.
template<int PPN>
__global__ __launch_bounds__(256)
void combine_kernel(const float* __restrict__ mP,
                    const float* __restrict__ sP,
                    const float* __restrict__ pP,
                    float* __restrict__ out)
{
    const int wgid = blockIdx.x * 4 + (threadIdx.x >> 6);   // = b*NN + n
    const int lane = threadIdx.x & 63;
    const size_t base = (size_t)wgid * PPN;

    float m = -INFINITY, s = 0.0f, p = 0.0f;
    if constexpr (PPN >= 64) {
#pragma unroll
        for (int j = 0; j < PPN / 64; ++j) {
            const size_t idx = base + lane + j * 64;
            const float mk = mP[idx], sk = sP[idx], pk = pP[idx];
            const float M  = fmaxf(m, mk);
            const float e1 = __expf(m - M), e2 = __expf(mk - M);
            s = s * e1 + sk * e2;
            p = p * e1 + pk * e2;
            m = M;
        }
    } else {
        if (lane < PPN) {
            m = mP[base + lane]; s = sP[base + lane]; p = pP[base + lane];
        }
    }

#pragma unroll
    for (int off = 1; off < 64; off <<= 1) {
        const float mo = __shfl_xor(m, off);
        const float so = __shfl_xor(s, off);
        const float po = __shfl_xor(p, off);
        const float M  = fmaxf(m, mo);
        const float e1 = __expf(m - M), e2 = __expf(mo - M);
        s = s * e1 + so * e2;
        p = p * e1 + po * e2;
        m = M;
    }

    if (lane == 0) out[wgid] = p / s;
}

extern "C" void kernel_launch(void* const* d_in, const int* in_sizes, int n_in,
                              void* d_out, int out_size, void* d_ws, size_t ws_size,
                              hipStream_t stream)
{
    (void)in_sizes; (void)n_in; (void)out_size;
    const float* data    = (const float*)d_in[0];
    const float* targets = (const float*)d_in[1];
    const float* W       = (const float*)d_in[2];
    float* out = (float*)d_out;

    constexpr int SEG = 8;
    const size_t plane4 = (size_t)BB * NN * (TT >> 4);   // GB=4: 128 partials/(b,n)
    const size_t plane6 = (size_t)BB * NN * (TT >> 6);   // GB=6: 32 partials/(b,n)
    const size_t segN   = (size_t)BB * SEG * TT;

    if (ws_size >= (3 * plane4 + segN) * sizeof(float)) {
        // 50 MB path: SEG=8, GB=4 (DPP-only reductions)
        float* mP = (float*)d_ws;
        float* sP = mP + plane4;
        float* pP = sP + plane4;
        float* sg = pP + plane4;
        segsum_kernel<SEG><<<BB * CHUNKS * SEG, 256, 0, stream>>>(data, targets, W, sg);
        scan_kernel<SEG, 4><<<BB * CHUNKS * SEG, 256, 0, stream>>>(data, targets, W, sg, mP, sP, pP);
        combine_kernel<128><<<(BB * NN) / 4, 256, 0, stream>>>(mP, sP, pP, out);
    } else if (ws_size >= (3 * plane6 + segN) * sizeof(float)) {
        // 14 MB path: SEG=8, GB=6
        float* mP = (float*)d_ws;
        float* sP = mP + plane6;
        float* pP = sP + plane6;
        float* sg = pP + plane6;
        segsum_kernel<SEG><<<BB * CHUNKS * SEG, 256, 0, stream>>>(data, targets, W, sg);
        scan_kernel<SEG, 6><<<BB * CHUNKS * SEG, 256, 0, stream>>>(data, targets, W, sg, mP, sP, pP);
        combine_kernel<32><<<(BB * NN) / 4, 256, 0, stream>>>(mP, sP, pP, out);
    } else {
        // 12 MB fallback: no segmentation (slow but correct)
        float* mP = (float*)d_ws;
        float* sP = mP + plane6;
        float* pP = sP + plane6;
        scan_kernel<1, 6><<<BB * CHUNKS, 256, 0, stream>>>(data, targets, W, nullptr, mP, sP, pP);
        combine_kernel<32><<<(BB * NN) / 4, 256, 0, stream>>>(mP, sP, pP, out);
    }
}